// Round 14
// baseline (505.253 us; speedup 1.0000x reference)
//
#include <hip/hip_runtime.h>
#include <hip/hip_bf16.h>

typedef __hip_bfloat16 bf16;
typedef unsigned short ushort;
typedef __attribute__((ext_vector_type(8))) short short8;   // 8 bf16 (4 VGPRs)
typedef __attribute__((ext_vector_type(4))) float f32x4;

__device__ __forceinline__ float dssp(float x){
  return fmaxf(x, 0.f) + __logf(1.f + __expf(-fabsf(x))) - 0.693147180559945f;
}
__device__ __forceinline__ int clampi(int x, int lo, int hi){ return x<lo?lo:(x>hi?hi:x); }
__device__ __forceinline__ ushort f2b(float f){
  unsigned x = __float_as_uint(f);
  return (ushort)((x + 0x7fffu + ((x>>16)&1u)) >> 16);
}
__device__ __forceinline__ float b2f16(ushort u){ return __uint_as_float(((unsigned)u)<<16); }

constexpr int TBL_K    = 4096;
constexpr int TBL_ROWS = TBL_K + 1;
constexpr int TBL_TILES = (TBL_ROWS + 31) / 32;  // 129

struct Seg { const void* src; float* dst; int n; };
struct SegTable { Seg s[18]; int count; long total; };
struct WSeg { const void* src; ushort* dst; int n; };
struct WTable { WSeg s[9]; int count; int total; };

// ---------------- K1: zero everything + dtype detect (block 0) --------------
__global__ void setup_all(const unsigned* __restrict__ raw, int* flag,
                          int* cnt_r, int* cnt_h, float* uacc,
                          int2* spk_r, int2* spk_h, int N, int E, int EH){
  __shared__ int c;
  int t = blockIdx.x*blockDim.x + threadIdx.x;
  if (t < N){ cnt_r[t]=0; cnt_h[t]=0; }
  if (t < 64) uacc[t]=0.f;
  if (t < E)  spk_r[t]=make_int2(0,0);
  if (t < EH) spk_h[t]=make_int2(0,0);
  if (blockIdx.x==0){
    if (threadIdx.x==0) c=0;
    __syncthreads();
    unsigned u  = raw[threadIdx.x];
    unsigned lo = u & 0xFFFFu;
    int e = (int)((lo >> 7) & 0xFF);
    int ok = (lo==0u) || (e >= 0x70 && e <= 0x8F);
    atomicAdd(&c, ok);
    __syncthreads();
    if (threadIdx.x==0) *flag = (c >= 160) ? 1 : 0;  // 1 = bf16 storage
  }
}

// ---------------- K2: f32 convert || bf16 weight convert || edge count ------
__global__ __launch_bounds__(256) void convert_count(SegTable tbl, WTable wt,
    const int* __restrict__ flag,
    const int* __restrict__ ei, const int* __restrict__ eih,
    int E, int EH, int N, int* cnt_r, int* cnt_h, int CA, int CB){
  int b = blockIdx.x;
  if (b < CA){
    int mode = *flag;
    long tid    = (long)b*256 + threadIdx.x;
    long stride = (long)CA*256;
    for (long i=tid; i<tbl.total; i+=stride){
      long off = i; int k = 0;
      while (k < tbl.count-1 && off >= tbl.s[k].n){ off -= tbl.s[k].n; k++; }
      float f;
      if (mode) f = __bfloat162float(((const bf16*)tbl.s[k].src)[off]);
      else      f = ((const float*)tbl.s[k].src)[off];
      tbl.s[k].dst[off] = (f==f) ? f : 0.f;
    }
  } else if (b < CA+CB){
    int mode = *flag;
    long tid    = (long)(b-CA)*256 + threadIdx.x;
    long stride = (long)CB*256;
    for (long i=tid; i<wt.total; i+=stride){
      long off = i; int k = 0;
      while (k < wt.count-1 && off >= wt.s[k].n){ off -= wt.s[k].n; k++; }
      if (mode) wt.s[k].dst[off] = ((const ushort*)wt.s[k].src)[off];
      else {
        float f = ((const float*)wt.s[k].src)[off];
        wt.s[k].dst[off] = f2b((f==f)? f : 0.f);
      }
    }
  } else {
    int t = (b-CA-CB)*256 + threadIdx.x;
    if (t < E)  atomicAdd(&cnt_r[clampi(ei[E + t], 0, N-1)], 1);
    if (t < EH) atomicAdd(&cnt_h[clampi(eih[EH + t], 0, N-1)], 1);
  }
}

__global__ __launch_bounds__(1024) void scan_pair(const int* cnt_r, int* off_r, int* cur_r,
                                                  const int* cnt_h, int* off_h, int* cur_h, int N){
  __shared__ int s[1024];
  int t = threadIdx.x;
  int CH = (N + 1023) / 1024;
  for (int which=0; which<2; which++){
    const int* cnt = which? cnt_h : cnt_r;
    int* off = which? off_h : off_r;
    int* cur = which? cur_h : cur_r;
    int base = t*CH;
    int sum = 0;
    for (int q=0;q<CH;q++){ int idx=base+q; sum += (idx<N)? cnt[idx] : 0; }
    __syncthreads();
    s[t]=sum; __syncthreads();
    for (int ofs=1; ofs<1024; ofs<<=1){
      int v = s[t]; int vp = (t>=ofs)? s[t-ofs] : 0;
      __syncthreads(); s[t]=v+vp; __syncthreads();
    }
    int run = (t>0)? s[t-1] : 0;
    for (int q=0;q<CH;q++){
      int idx=base+q;
      if (idx<N){ off[idx]=run; cur[idx]=run; run += cnt[idx]; }
    }
    if (t==1023) off[N] = s[1023];
  }
}

// ---------------- K4: scatter edges || build W-table ------------------------
__global__ __launch_bounds__(256) void scatter_build(
    const int* __restrict__ ei, const float* __restrict__ distc,
    const int* __restrict__ eih, int E, int EH, int N,
    int* cur_r, int* cur_h, int2* spk_r, int2* spk_h,
    const float* __restrict__ mlp_w1, const float* __restrict__ mlp_b1,
    const float* __restrict__ mlp_w2, const float* __restrict__ mlp_b2,
    ushort* __restrict__ Wtab, int nbE){
  __shared__ __align__(16) char smem[36352];
  if ((int)blockIdx.x < nbE){
    int t = blockIdx.x*256 + threadIdx.x;
    if (t < E){
      int i = clampi(ei[E+t], 0, N-1);
      int p = clampi(atomicAdd(&cur_r[i], 1), 0, E-1);
      float x = fminf(fmaxf(distc[t]*(4096.0f/5.0f), 0.f), 4095.999f);
      int i0 = (int)x; if (i0 > TBL_K-1) i0 = TBL_K-1;
      unsigned fr16 = (unsigned)((x - (float)i0)*65536.0f); if (fr16 > 65535u) fr16 = 65535u;
      spk_r[p] = make_int2(clampi(ei[t],0,N-1), (int)(((unsigned)i0<<16)|fr16));
    }
    if (t < EH){
      int ih = clampi(eih[EH+t], 0, N-1);
      int p = clampi(atomicAdd(&cur_h[ih], 1), 0, EH-1);
      spk_h[p] = make_int2(clampi(eih[t],0,N-1), t);
    }
    return;
  }
  // ---- build_wtab (proven body) ----
  int bid  = blockIdx.x - nbE;
  int l    = bid / TBL_TILES;
  int tile = bid % TBL_TILES;
  int row0 = tile * 32;
  const float* w1 = mlp_w1 + l*128*25;
  const float* b1 = mlp_b1 + l*128;
  const float* w2 = mlp_w2 + l*128*128;
  const float* b2 = mlp_b2 + l*128;
  float (*Gs)[26]  = (float(*)[26])smem;            // 3328 B
  float (*Ts)[129] = (float(*)[129])(smem+3328);    // 16512 B
  float (*Ws)[129] = (float(*)[129])(smem+19840);   // 16512 B
  int t = threadIdx.x;
  for (int idx=t; idx<32*25; idx+=256){
    int r = idx/25, k = idx%25;
    float d = (row0+r) * (5.0f/4096.0f);
    float x = d - (float)k*(5.0f/24.0f);
    Gs[r][k] = __expf(-11.52f*x*x);
  }
  __syncthreads();
  int rg = t&7, cg = t>>3;
  #pragma unroll
  for (int ri=0;ri<4;ri++){
    int r = rg*4+ri;
    #pragma unroll
    for (int ci=0;ci<4;ci++){
      int c = cg*4+ci;
      float s = b1[c];
      for (int k=0;k<25;k++) s += Gs[r][k]*w1[c*25+k];
      Ts[r][c] = dssp(s);
    }
  }
  float acc[4][4] = {};
  for (int k0=0;k0<128;k0+=32){
    __syncthreads();
    for (int idx=t; idx<1024; idx+=256){
      int c=idx>>3, kk4=(idx&7)*4;
      float4 f = *(const float4*)(w2+(size_t)c*128+k0+kk4);
      Ws[kk4][c]=f.x; Ws[kk4+1][c]=f.y; Ws[kk4+2][c]=f.z; Ws[kk4+3][c]=f.w;
    }
    __syncthreads();
    for (int kk=0;kk<32;kk++){
      float xv[4];
      #pragma unroll
      for (int ri=0;ri<4;ri++) xv[ri]=Ts[rg*4+ri][k0+kk];
      #pragma unroll
      for (int ci=0;ci<4;ci++){
        float wv = Ws[kk][cg*4+ci];
        #pragma unroll
        for (int ri=0;ri<4;ri++) acc[ri][ci] += xv[ri]*wv;
      }
    }
  }
  #pragma unroll
  for (int ri=0;ri<4;ri++){
    int r = row0 + rg*4 + ri;
    if (r >= TBL_ROWS) continue;
    float d  = r * (5.0f/4096.0f);
    float Cf = 0.5f*(cosf(d*(3.14159265358979f/5.0f))+1.0f);
    #pragma unroll
    for (int ci=0;ci<4;ci++){
      int c = cg*4+ci;
      Wtab[((size_t)l*TBL_ROWS + r)*128 + c] = f2b((acc[ri][ci] + b2[c]) * Cf);
    }
  }
}

// ------------------------------ MFMA tile helpers ---------------------------
__device__ __forceinline__ short8 afragb(const ushort (*Xb)[136], int lane, int k0){
  int m=lane&15, q=(lane>>4)&3;
  return *(const short8*)(&Xb[m][k0+q*8]);
}
__device__ __forceinline__ short8 bfrag(const ushort* __restrict__ W, int cbase, int lane, int k0){
  int n=lane&15, q=(lane>>4)&3;
  return *(const short8*)(W + (size_t)(cbase+n)*128 + k0 + q*8);
}
template<int NT>
__device__ __forceinline__ void mgemm(const ushort (*Xb)[136],
    const ushort* __restrict__ W, int t, f32x4 d[NT]){
  int lane=t&63, w=t>>6;
  #pragma unroll
  for (int ct=0;ct<NT;ct++) d[ct]=(f32x4){0.f,0.f,0.f,0.f};
  #pragma unroll
  for (int kc=0;kc<4;kc++){
    short8 a = afragb(Xb, lane, kc*32);
    #pragma unroll
    for (int ct=0;ct<NT;ct++){
      short8 b = bfrag(W, w*(NT*16)+ct*16, lane, kc*32);
      d[ct] = __builtin_amdgcn_mfma_f32_16x16x32_bf16(a, b, d[ct], 0, 0, 0);
    }
  }
}
template<int NT>
__device__ __forceinline__ void d2tile(ushort (*Y)[136], const f32x4 d[NT], int t,
    int colofs, const float* __restrict__ bias, int do_ssp){
  int lane=t&63, w=t>>6, q=(lane>>4)&3, n=lane&15;
  #pragma unroll
  for (int ct=0;ct<NT;ct++){
    int c = w*(NT*16)+ct*16+n;
    float bv = bias? bias[c] : 0.f;
    #pragma unroll
    for (int i=0;i<4;i++){
      float y = d[ct][i] + bv;
      if (do_ssp) y = dssp(y);
      Y[q*4+i][colofs+c] = f2b(y);
    }
  }
}
template<int NT>
__device__ __forceinline__ void d2os(float (*Os)[132], const f32x4 d[NT], int t,
    const float* __restrict__ bias, int do_ssp){
  int lane=t&63, w=t>>6, q=(lane>>4)&3, n=lane&15;
  #pragma unroll
  for (int ct=0;ct<NT;ct++){
    int c = w*(NT*16)+ct*16+n;
    float bv = bias? bias[c] : 0.f;
    #pragma unroll
    for (int i=0;i<4;i++){
      float y = d[ct][i] + bv;
      if (do_ssp) y = dssp(y);
      Os[q*4+i][c] = y;
    }
  }
}
__device__ __forceinline__ void d2glob_c(ushort* __restrict__ out, const f32x4 d[2],
    int t, int row0, int N, ushort (*Tmp)[136]){
  d2tile<2>(Tmp, d, t, 0, nullptr, 0);
  __syncthreads();
  int r=t>>4, o=(t&15)*8;
  int gr=row0+r;
  if (gr<N) *(uint4*)(out + (size_t)gr*128 + o) = *(const uint4*)&Tmp[r][o];
  __syncthreads();
}

// ---- device bodies for hull tile + f_first tile (shared-mem passed in) -----
__device__ void hull_body(int bid, const int2* __restrict__ spk_h,
    const float* __restrict__ fea,
    const float* __restrict__ mlph_w1, const float* __restrict__ mlph_b1,
    const ushort* __restrict__ mlph_w2b, const float* __restrict__ mlph_b2,
    ushort* __restrict__ WhS_base, size_t lstride,
    int EH, int tilesPerLayer, int l0, char* smem){
  int l    = l0 + bid / tilesPerLayer;
  int tile = bid % tilesPerLayer;
  int row0 = tile*64;
  const float* w1 = mlph_w1 + l*128*7;
  const float* b1 = mlph_b1 + l*128;
  const ushort* w2 = mlph_w2b + (size_t)l*16384;
  const float* b2 = mlph_b2 + l*128;
  ushort* WhS = WhS_base + (size_t)(l-l0)*lstride;
  int*   Eid = (int*)smem;                       // 256 B
  float (*Fs)[8] = (float(*)[8])(smem+256);      // 2048 B
  ushort (*Buf)[136] = (ushort(*)[136])(smem+2304); // 17408 B
  int t=threadIdx.x;
  if (t < 64){
    int p=row0+t;
    Eid[t]=(p<EH)? clampi(spk_h[p].y,0,EH-1):0;
  }
  __syncthreads();
  for (int idx=t; idx<448; idx+=256){
    int r=idx/7, k=idx%7;
    int p=row0+r;
    Fs[r][k]=(p<EH)? fea[(size_t)Eid[r]*7+k]:0.f;
  }
  __syncthreads();
  {
    int c0=(t&31)*4, r0=(t>>5)*8;
    float w[4][7]; float bb[4];
    #pragma unroll
    for (int cc=0;cc<4;cc++){
      bb[cc]=b1[c0+cc];
      #pragma unroll
      for (int k=0;k<7;k++) w[cc][k]=w1[(c0+cc)*7+k];
    }
    #pragma unroll
    for (int rr=0;rr<8;rr++){
      int r=r0+rr;
      float fv[7];
      #pragma unroll
      for (int k=0;k<7;k++) fv[k]=Fs[r][k];
      ushort o[4];
      #pragma unroll
      for (int cc=0;cc<4;cc++){
        float s=bb[cc];
        #pragma unroll
        for (int k=0;k<7;k++) s=fmaf(fv[k],w[cc][k],s);
        o[cc]=f2b(dssp(s));
      }
      unsigned lo=(unsigned)o[0]|((unsigned)o[1]<<16);
      unsigned hi=(unsigned)o[2]|((unsigned)o[3]<<16);
      *(uint2*)&Buf[r][c0]=make_uint2(lo,hi);
    }
  }
  __syncthreads();
  int lane=t&63, w=t>>6;
  const ushort (*Xw)[136] = (const ushort (*)[136])&Buf[w*16][0];
  f32x4 d[8];
  #pragma unroll
  for (int ct=0;ct<8;ct++) d[ct]=(f32x4){0.f,0.f,0.f,0.f};
  #pragma unroll
  for (int kc=0;kc<4;kc++){
    short8 a = afragb(Xw, lane, kc*32);
    #pragma unroll
    for (int ct=0;ct<8;ct++){
      short8 b = bfrag(w2, ct*16, lane, kc*32);
      d[ct] = __builtin_amdgcn_mfma_f32_16x16x32_bf16(a, b, d[ct], 0, 0, 0);
    }
  }
  __syncthreads();
  int q=(lane>>4)&3, n=lane&15;
  #pragma unroll
  for (int ct=0;ct<8;ct++){
    int c=ct*16+n;
    float bv=b2[c];
    #pragma unroll
    for (int i=0;i<4;i++)
      Buf[w*16+q*4+i][c] = f2b(d[ct][i]+bv);
  }
  __syncthreads();
  #pragma unroll
  for (int j=0;j<4;j++){
    int idx=j*256+t;
    int r=idx>>4, o=(idx&15)*8;
    *(uint4*)(WhS + (size_t)(row0+r)*128 + o) = *(const uint4*)&Buf[r][o];
  }
}

__device__ void f_first_body(int bid, const int* __restrict__ z,
    const float* __restrict__ emb, float* __restrict__ v,
    const ushort* __restrict__ linA, const ushort* __restrict__ linB,
    ushort* __restrict__ vlin, ushort* __restrict__ vlinh, int N, char* smem){
  ushort (*Xb)[136] = (ushort(*)[136])smem;          // 4352 B
  ushort (*Tb)[136] = (ushort(*)[136])(smem+4352);   // 4352 B
  int t=threadIdx.x; int row0=bid*16;
  f32x4 d[2];
  for (int idx=t; idx<512; idx+=256){
    int r=idx>>5, k4=(idx&31)*4; int gr=row0+r;
    int zz=(gr<N)? clampi(z[gr],0,99):0;
    float4 f = *(const float4*)(emb + (size_t)zz*128 + k4);
    unsigned r0 = (unsigned)f2b(f.x) | ((unsigned)f2b(f.y)<<16);
    unsigned r1 = (unsigned)f2b(f.z) | ((unsigned)f2b(f.w)<<16);
    *(uint2*)&Xb[r][k4] = make_uint2(r0,r1);
    if (gr<N) *(float4*)(v + (size_t)gr*128 + k4) = f;
  }
  __syncthreads();
  mgemm<2>(Xb, linA, t, d);
  d2glob_c(vlin, d, t, row0, N, Tb);
  mgemm<2>(Xb, linB, t, d);
  d2glob_c(vlinh, d, t, row0, N, Tb);
}

// ------- K5: hull (all layers) || f_first || pack_wtab ----------------------
__global__ __launch_bounds__(256) void hull_pack_first(const int2* __restrict__ spk_h,
    const float* __restrict__ fea,
    const float* __restrict__ mlph_w1, const float* __restrict__ mlph_b1,
    const ushort* __restrict__ mlph_w2b, const float* __restrict__ mlph_b2,
    ushort* __restrict__ WhS, size_t lstride, int EH, int ht64,
    const int* __restrict__ z, const float* __restrict__ emb, float* __restrict__ v,
    const ushort* __restrict__ linA, const ushort* __restrict__ linB,
    ushort* __restrict__ vlin, ushort* __restrict__ vlinh, int N, int nt,
    const ushort* __restrict__ Wtab, unsigned* __restrict__ Wpk, int PB, int HB){
  __shared__ __align__(16) char smem[19968];
  int b = blockIdx.x;
  if (b < HB){
    hull_body(b, spk_h, fea, mlph_w1, mlph_b1, mlph_w2b, mlph_b2,
              WhS, lstride, EH, ht64, 0, smem);
  } else if (b < HB+nt){
    f_first_body(b-HB, z, emb, v, linA, linB, vlin, vlinh, N, smem);
  } else {
    long tid    = (long)(b-HB-nt)*256 + threadIdx.x;
    long stride = (long)PB*256;
    const long TOT = 4L*TBL_K*128;
    for (long i=tid; i<TOT; i+=stride){
      int l = (int)(i / ((long)TBL_K*128));
      long rem = i % ((long)TBL_K*128);
      int r = (int)(rem >> 7), f = (int)(rem & 127);
      const ushort* base = Wtab + (size_t)l*TBL_ROWS*128;
      Wpk[i] = (((unsigned)base[(size_t)(r+1)*128+f])<<16) | (unsigned)base[(size_t)r*128+f];
    }
  }
}

// standalone hull (fallback when workspace can't hold 4 layers)
__global__ __launch_bounds__(256) void hull_all(const int2* __restrict__ spk_h,
    const float* __restrict__ fea,
    const float* __restrict__ mlph_w1, const float* __restrict__ mlph_b1,
    const ushort* __restrict__ mlph_w2b, const float* __restrict__ mlph_b2,
    ushort* __restrict__ WhS_base, size_t lstride,
    int EH, int tilesPerLayer, int l0){
  __shared__ __align__(16) char smem[19968];
  hull_body(blockIdx.x, spk_h, fea, mlph_w1, mlph_b1, mlph_w2b, mlph_b2,
            WhS_base, lstride, EH, tilesPerLayer, l0, smem);
}

// -------------- F_mid: update_v(l) + lin(l+1) + linh(l+1) -------------------
__global__ __launch_bounds__(256) void f_mid(
    const float* __restrict__ accR, const float* __restrict__ accH,
    float* __restrict__ v,
    const ushort* __restrict__ v1w, const float* __restrict__ v1b,
    const ushort* __restrict__ v2w, const float* __restrict__ v2b,
    const ushort* __restrict__ vh1w, const float* __restrict__ vh1b,
    const ushort* __restrict__ vh2w, const float* __restrict__ vh2b,
    const ushort* __restrict__ cw, const float* __restrict__ cb,
    const ushort* __restrict__ linA, const ushort* __restrict__ linB,
    ushort* __restrict__ vlin, ushort* __restrict__ vlinh, int N){
  __shared__ ushort Xb[16][136];
  __shared__ ushort Xb2[16][136];
  __shared__ ushort Xb3[16][136];
  __shared__ float  Os[16][132];
  int t=threadIdx.x; int row0=blockIdx.x*16;
  f32x4 d[2]; f32x4 d1[1];

  for (int path=0; path<2; path++){
    const float* X = path? accH : accR;
    __syncthreads();
    for (int idx=t; idx<512; idx+=256){
      int r=idx>>5, k4=(idx&31)*4; int gr=row0+r;
      float4 f=(gr<N)? *(const float4*)(X+(size_t)gr*128+k4):make_float4(0,0,0,0);
      unsigned r0 = (unsigned)f2b(f.x) | ((unsigned)f2b(f.y)<<16);
      unsigned r1 = (unsigned)f2b(f.z) | ((unsigned)f2b(f.w)<<16);
      *(uint2*)&Xb[r][k4] = make_uint2(r0,r1);
    }
    __syncthreads();
    mgemm<2>(Xb, path?vh1w:v1w, t, d);
    d2tile<2>(Xb2, d, t, 0, path?vh1b:v1b, 1);
    __syncthreads();
    mgemm<1>(Xb2, path?vh2w:v2w, t, d1);
    d2tile<1>(Xb3, d1, t, path*64, path?vh2b:v2b, 0);
  }
  __syncthreads();
  mgemm<2>(Xb3, cw, t, d);
  d2os<2>(Os, d, t, cb, 1);
  __syncthreads();
  for (int idx=t; idx<512; idx+=256){      // v += Os ; Xb = bf16(new v)
    int r=idx>>5, k4=(idx&31)*4; int gr=row0+r;
    float4 f=(gr<N)? *(const float4*)(v+(size_t)gr*128+k4):make_float4(0,0,0,0);
    f.x+=Os[r][k4]; f.y+=Os[r][k4+1]; f.z+=Os[r][k4+2]; f.w+=Os[r][k4+3];
    if (gr<N) *(float4*)(v+(size_t)gr*128+k4)=f;
    unsigned r0 = (unsigned)f2b(f.x) | ((unsigned)f2b(f.y)<<16);
    unsigned r1 = (unsigned)f2b(f.z) | ((unsigned)f2b(f.w)<<16);
    *(uint2*)&Xb[r][k4] = make_uint2(r0,r1);
  }
  __syncthreads();
  mgemm<2>(Xb, linA, t, d);
  d2glob_c(vlin, d, t, row0, N, Xb2);
  mgemm<2>(Xb, linB, t, d);
  d2glob_c(vlinh, d, t, row0, N, Xb2);
}

// -------------- F_last: update_v(3) + readout (update_u) --------------------
__global__ __launch_bounds__(256) void f_last(
    const float* __restrict__ accR, const float* __restrict__ accH,
    const float* __restrict__ v,
    const ushort* __restrict__ v1w, const float* __restrict__ v1b,
    const ushort* __restrict__ v2w, const float* __restrict__ v2b,
    const ushort* __restrict__ vh1w, const float* __restrict__ vh1b,
    const ushort* __restrict__ vh2w, const float* __restrict__ vh2b,
    const ushort* __restrict__ cw, const float* __restrict__ cb,
    const ushort* __restrict__ u1w, const float* __restrict__ u1b,
    const float* __restrict__ u2w, const float* __restrict__ u2b,
    const int* __restrict__ batch, float* __restrict__ uacc, int N){
  __shared__ ushort Xb[16][136];
  __shared__ ushort Xb2[16][136];
  __shared__ ushort Xb3[16][136];
  __shared__ float  Os[16][132];
  __shared__ float ss[16];
  __shared__ int   bb[16];
  int t=threadIdx.x; int row0=blockIdx.x*16;
  f32x4 d[2]; f32x4 d1[1];

  for (int path=0; path<2; path++){
    const float* X = path? accH : accR;
    __syncthreads();
    for (int idx=t; idx<512; idx+=256){
      int r=idx>>5, k4=(idx&31)*4; int gr=row0+r;
      float4 f=(gr<N)? *(const float4*)(X+(size_t)gr*128+k4):make_float4(0,0,0,0);
      unsigned r0 = (unsigned)f2b(f.x) | ((unsigned)f2b(f.y)<<16);
      unsigned r1 = (unsigned)f2b(f.z) | ((unsigned)f2b(f.w)<<16);
      *(uint2*)&Xb[r][k4] = make_uint2(r0,r1);
    }
    __syncthreads();
    mgemm<2>(Xb, path?vh1w:v1w, t, d);
    d2tile<2>(Xb2, d, t, 0, path?vh1b:v1b, 1);
    __syncthreads();
    mgemm<1>(Xb2, path?vh2w:v2w, t, d1);
    d2tile<1>(Xb3, d1, t, path*64, path?vh2b:v2b, 0);
  }
  __syncthreads();
  mgemm<2>(Xb3, cw, t, d);
  d2os<2>(Os, d, t, cb, 1);
  __syncthreads();
  for (int idx=t; idx<512; idx+=256){      // Xb = bf16(v + dssp(cat))
    int r=idx>>5, k4=(idx&31)*4; int gr=row0+r;
    float4 f=(gr<N)? *(const float4*)(v+(size_t)gr*128+k4):make_float4(0,0,0,0);
    f.x+=Os[r][k4]; f.y+=Os[r][k4+1]; f.z+=Os[r][k4+2]; f.w+=Os[r][k4+3];
    unsigned r0 = (unsigned)f2b(f.x) | ((unsigned)f2b(f.y)<<16);
    unsigned r1 = (unsigned)f2b(f.z) | ((unsigned)f2b(f.w)<<16);
    *(uint2*)&Xb[r][k4] = make_uint2(r0,r1);
  }
  __syncthreads();
  mgemm<1>(Xb, u1w, t, d1);                // 64 cols
  d2os<1>(Os, d1, t, u1b, 1);
  __syncthreads();
  if (t<16){
    int gr=row0+t;
    float s=0.f; int bt=-1;
    if (gr<N){
      s = u2b[0];
      for (int c=0;c<64;c++) s += Os[t][c]*u2w[c];
      bt = clampi(batch[gr],0,63);
    }
    ss[t]=s; bb[t]=bt;
  }
  __syncthreads();
  if (t==0){
    float run=0.f; int cur=-1;
    for (int q=0;q<16;q++){
      int bq=bb[q];
      if (bq<0) continue;
      if (bq!=cur){ if (cur>=0) atomicAdd(&uacc[cur],run); cur=bq; run=0.f; }
      run += ss[q];
    }
    if (cur>=0) atomicAdd(&uacc[cur],run);
  }
}

// ------------------------------ CSR segment reductions ----------------------
__device__ __forceinline__ float rlerp(unsigned y, const unsigned* __restrict__ Wpk, int f){
  int i0 = (int)(y>>16);
  float fr = (float)(y&0xFFFFu)*(1.f/65536.f);
  unsigned u = Wpk[(size_t)i0*128+f];
  float w0=__uint_as_float(u<<16), w1=__uint_as_float(u&0xFFFF0000u);
  return fmaf(fr, w1-w0, w0);
}

__global__ __launch_bounds__(128) void acc_both(
    const int* __restrict__ off_r, const int2* __restrict__ spk_r,
    const ushort* __restrict__ vlin, const unsigned* __restrict__ Wpk,
    float* __restrict__ accR,
    const int* __restrict__ off_h, const int2* __restrict__ spk_h,
    const ushort* __restrict__ vlinh, const ushort* __restrict__ WhS,
    float* __restrict__ accH,
    int Etot, int EHtot, int N){
  int f = threadIdx.x;
  if ((int)blockIdx.x < N){
    int n = blockIdx.x;
    int b = clampi(off_r[n], 0, Etot);
    int e = clampi(off_r[n+1], b, Etot);
    float a = 0.f;
    int p = b;
    for (; p+8<=e; p+=8){
      int2 k[8];
      #pragma unroll
      for (int j=0;j<8;j++) k[j]=spk_r[p+j];
      float vv[8], ww[8];
      #pragma unroll
      for (int j=0;j<8;j++) vv[j]=b2f16(vlin[(size_t)k[j].x*128+f]);
      #pragma unroll
      for (int j=0;j<8;j++) ww[j]=rlerp((unsigned)k[j].y, Wpk, f);
      #pragma unroll
      for (int j=0;j<8;j++) a=fmaf(vv[j],ww[j],a);
    }
    for (; p+4<=e; p+=4){
      int2 k0=spk_r[p], k1=spk_r[p+1], k2=spk_r[p+2], k3=spk_r[p+3];
      float v0 = b2f16(vlin[(size_t)k0.x*128+f]);
      float v1 = b2f16(vlin[(size_t)k1.x*128+f]);
      float v2 = b2f16(vlin[(size_t)k2.x*128+f]);
      float v3 = b2f16(vlin[(size_t)k3.x*128+f]);
      float w0 = rlerp((unsigned)k0.y, Wpk, f);
      float w1 = rlerp((unsigned)k1.y, Wpk, f);
      float w2 = rlerp((unsigned)k2.y, Wpk, f);
      float w3 = rlerp((unsigned)k3.y, Wpk, f);
      a += v0*w0 + v1*w1 + v2*w2 + v3*w3;
    }
    for (; p<e; p++){
      int2 k0=spk_r[p];
      a += b2f16(vlin[(size_t)k0.x*128+f]) * rlerp((unsigned)k0.y, Wpk, f);
    }
    accR[(size_t)n*128+f] = a;
  } else {
    int n = blockIdx.x - N;
    int b = clampi(off_h[n], 0, EHtot);
    int e = clampi(off_h[n+1], b, EHtot);
    float a = 0.f;
    int p = b;
    for (; p+4<=e; p+=4){
      int2 k0=spk_h[p], k1=spk_h[p+1], k2=spk_h[p+2], k3=spk_h[p+3];
      float v0 = b2f16(vlinh[(size_t)k0.x*128+f]);
      float v1 = b2f16(vlinh[(size_t)k1.x*128+f]);
      float v2 = b2f16(vlinh[(size_t)k2.x*128+f]);
      float v3 = b2f16(vlinh[(size_t)k3.x*128+f]);
      a += v0*b2f16(WhS[(size_t)p*128+f])     + v1*b2f16(WhS[(size_t)(p+1)*128+f])
         + v2*b2f16(WhS[(size_t)(p+2)*128+f]) + v3*b2f16(WhS[(size_t)(p+3)*128+f]);
    }
    for (; p<e; p++){
      int2 k0=spk_h[p];
      a += b2f16(vlinh[(size_t)k0.x*128+f]) * b2f16(WhS[(size_t)p*128+f]);
    }
    accH[(size_t)n*128+f] = a;
  }
}

__global__ void write_out(const float* __restrict__ uacc, void* out, const int* __restrict__ flag){
  int t = threadIdx.x;
  if (t < 64){
    if (*flag) ((bf16*)out)[t] = __float2bfloat16(uacc[t]);
    else       ((float*)out)[t] = uacc[t];
  }
}

// ----------------------------------------------------------------- launch ---
extern "C" void kernel_launch(void* const* d_in, const int* in_sizes, int n_in,
                              void* d_out, int out_size, void* d_ws, size_t ws_size,
                              hipStream_t stream){
  const int* z     = (const int*)d_in[0];
  const int* ei    = (const int*)d_in[1];
  const int* eih   = (const int*)d_in[2];
  const int* batch = (const int*)d_in[3];

  const int N  = in_sizes[0];
  const int E  = in_sizes[1]/2;
  const int EH = in_sizes[2]/2;
  const int EHpad = (EH + 63) & ~63;

  char* wp = (char*)d_ws;
  auto alloc = [&](size_t bytes)->char*{
    char* p = wp; wp += (bytes + 255) & ~(size_t)255; return p;
  };
  int* flag    = (int*)alloc(256);
  int* cnt_r   = (int*)alloc((size_t)N*4);
  int* off_r   = (int*)alloc((size_t)(N+1)*4);
  int* cur_r   = (int*)alloc((size_t)N*4);
  int* cnt_h   = (int*)alloc((size_t)N*4);
  int* off_h   = (int*)alloc((size_t)(N+1)*4);
  int* cur_h   = (int*)alloc((size_t)N*4);
  int2* spk_r  = (int2*)alloc((size_t)E*8);
  int2* spk_h  = (int2*)alloc((size_t)EH*8);
  float* uacc  = (float*)alloc(64*4);

  // fp32 canonical copies: only tensors consumed as fp32 downstream
  static const int f32_idx[18] = {0,1,2,4,5,6,7,9,10,12,14,16,18,20,22,24,25,26};
  float* cvt[27] = {};
  SegTable tbl; tbl.count = 18; tbl.total = 0;
  for (int k=0;k<18;k++){
    int i = f32_idx[k];
    int n = in_sizes[4+i];
    cvt[i] = (float*)alloc((size_t)n*4);
    tbl.s[k].src = d_in[4+i];
    tbl.s[k].dst = cvt[i];
    tbl.s[k].n   = n;
    tbl.total   += n;
  }
  const float* distc   = cvt[0];
  const float* feac    = cvt[1];
  const float* embc    = cvt[2];
  const float* mlp_w1  = cvt[4];
  const float* mlp_b1  = cvt[5];
  const float* mlp_w2  = cvt[6];
  const float* mlp_b2  = cvt[7];
  const float* mlph_w1 = cvt[9];
  const float* mlph_b1 = cvt[10];
  const float* mlph_b2 = cvt[12];
  const float* v1_b  = cvt[14];
  const float* v2_b  = cvt[16];
  const float* vh1_b = cvt[18];
  const float* vh2_b = cvt[20];
  const float* cat_b = cvt[22];
  const float* u1_b  = cvt[24];
  const float* u2_w  = cvt[25];
  const float* u2_b  = cvt[26];

  // bf16 weight copies, converted directly from inputs
  ushort* lin_wb   = (ushort*)alloc((size_t)4*16384*2);
  ushort* linh_wb  = (ushort*)alloc((size_t)4*16384*2);
  ushort* v1_wb    = (ushort*)alloc((size_t)4*16384*2);
  ushort* vh1_wb   = (ushort*)alloc((size_t)4*16384*2);
  ushort* cat_wb   = (ushort*)alloc((size_t)4*16384*2);
  ushort* mlph_w2b = (ushort*)alloc((size_t)4*16384*2);
  ushort* v2_wb    = (ushort*)alloc((size_t)4*8192*2);
  ushort* vh2_wb   = (ushort*)alloc((size_t)4*8192*2);
  ushort* u1_wb    = (ushort*)alloc((size_t)8192*2);
  WTable wt; wt.count = 9;
  wt.s[0] = { d_in[4+3],  lin_wb,   4*16384 };
  wt.s[1] = { d_in[4+8],  linh_wb,  4*16384 };
  wt.s[2] = { d_in[4+11], mlph_w2b, 4*16384 };
  wt.s[3] = { d_in[4+13], v1_wb,    4*16384 };
  wt.s[4] = { d_in[4+15], v2_wb,    4*8192  };
  wt.s[5] = { d_in[4+17], vh1_wb,   4*16384 };
  wt.s[6] = { d_in[4+19], vh2_wb,   4*8192  };
  wt.s[7] = { d_in[4+21], cat_wb,   4*16384 };
  wt.s[8] = { d_in[4+23], u1_wb,    8192    };
  wt.total = 6*4*16384 + 2*4*8192 + 8192;

  ushort*   Wtab = (ushort*)alloc((size_t)4*TBL_ROWS*128*2);
  unsigned* Wpk  = (unsigned*)alloc((size_t)4*TBL_K*128*4);
  float* v     = (float*)alloc((size_t)N*128*4);
  ushort* vlin  = (ushort*)alloc((size_t)N*128*2);
  ushort* vlinh = (ushort*)alloc((size_t)N*128*2);
  float* accR  = (float*)alloc((size_t)N*128*4);
  float* accH  = (float*)alloc((size_t)N*128*4);

  size_t used = (size_t)(wp - (char*)d_ws);
  size_t whs1 = (size_t)EHpad*128*2;
  bool pre = (ws_size >= used + 4*whs1 + 256);
  ushort* WhS = (ushort*)alloc(pre ? 4*whs1 : whs1);

  const int nbE  = (E+255)/256;
  const int nt   = (N+15)/16;
  const int ht64 = (EH+63)/64;
  const int CA = 1536, CB = 1024, PB = 1024;

  // K1: zero + detect
  setup_all<<<nbE,256,0,stream>>>((const unsigned*)d_in[6], flag,
                                  cnt_r, cnt_h, uacc, spk_r, spk_h, N, E, EH);
  // K2: convert (f32 + bf16) || count
  convert_count<<<CA+CB+nbE,256,0,stream>>>(tbl, wt, flag, ei, eih, E, EH, N,
                                            cnt_r, cnt_h, CA, CB);
  // K3: scan
  scan_pair<<<1,1024,0,stream>>>(cnt_r,off_r,cur_r,cnt_h,off_h,cur_h,N);
  // K4: scatter || build_wtab
  scatter_build<<<nbE + 4*TBL_TILES,256,0,stream>>>(ei, distc, eih, E, EH, N,
      cur_r, cur_h, spk_r, spk_h, mlp_w1, mlp_b1, mlp_w2, mlp_b2, Wtab, nbE);
  // K5: hull(all layers, if pre) || f_first || pack_wtab
  {
    int HB = pre ? 4*ht64 : 0;
    hull_pack_first<<<HB+nt+PB,256,0,stream>>>(spk_h, feac, mlph_w1, mlph_b1,
        mlph_w2b, mlph_b2, WhS, whs1/2, EH, ht64,
        z, embc, v, lin_wb, linh_wb, vlin, vlinh, N, nt,
        Wtab, Wpk, PB, HB);
  }

  for (int l=0;l<4;l++){
    if (!pre)
      hull_all<<<ht64,256,0,stream>>>(spk_h, feac, mlph_w1, mlph_b1, mlph_w2b, mlph_b2,
                                      WhS, 0, EH, ht64, l);
    const ushort* WhSl = pre ? (WhS + (size_t)l*(whs1/2)) : WhS;
    acc_both<<<2*N,128,0,stream>>>(off_r, spk_r, vlin, Wpk + (size_t)l*TBL_K*128, accR,
                                   off_h, spk_h, vlinh, WhSl, accH, E, EH, N);
    if (l<3){
      f_mid<<<nt,256,0,stream>>>(accR, accH, v,
          v1_wb + (size_t)l*16384, v1_b + l*128, v2_wb + (size_t)l*8192, v2_b + l*64,
          vh1_wb + (size_t)l*16384, vh1_b + l*128, vh2_wb + (size_t)l*8192, vh2_b + l*64,
          cat_wb + (size_t)l*16384, cat_b + l*128,
          lin_wb + (size_t)(l+1)*16384, linh_wb + (size_t)(l+1)*16384, vlin, vlinh, N);
    } else {
      f_last<<<nt,256,0,stream>>>(accR, accH, v,
          v1_wb + (size_t)l*16384, v1_b + l*128, v2_wb + (size_t)l*8192, v2_b + l*64,
          vh1_wb + (size_t)l*16384, vh1_b + l*128, vh2_wb + (size_t)l*8192, vh2_b + l*64,
          cat_wb + (size_t)l*16384, cat_b + l*128,
          u1_wb, u1_b, u2_w, u2_b, batch, uacc, N);
    }
  }
  write_out<<<1,64,0,stream>>>(uacc, d_out, flag);
}

// Round 15
// 463.743 us; speedup vs baseline: 1.0895x; 1.0895x over previous
//
#include <hip/hip_runtime.h>
#include <hip/hip_bf16.h>

typedef __hip_bfloat16 bf16;
typedef unsigned short ushort;
typedef __attribute__((ext_vector_type(8))) short short8;   // 8 bf16 (4 VGPRs)
typedef __attribute__((ext_vector_type(4))) float f32x4;

__device__ __forceinline__ float dssp(float x){
  return fmaxf(x, 0.f) + __logf(1.f + __expf(-fabsf(x))) - 0.693147180559945f;
}
__device__ __forceinline__ int clampi(int x, int lo, int hi){ return x<lo?lo:(x>hi?hi:x); }
__device__ __forceinline__ ushort f2b(float f){
  unsigned x = __float_as_uint(f);
  return (ushort)((x + 0x7fffu + ((x>>16)&1u)) >> 16);
}
__device__ __forceinline__ float b2f16(ushort u){ return __uint_as_float(((unsigned)u)<<16); }

constexpr int TBL_K    = 4096;
constexpr int TBL_ROWS = TBL_K + 1;
constexpr int TBL_T16  = (TBL_ROWS + 15) / 16;   // 257

struct Seg { const void* src; float* dst; int n; };
struct SegTable { Seg s[18]; int count; long total; };
struct WSeg { const void* src; ushort* dst; int n; };
struct WTable { WSeg s[10]; int count; int total; };

// ---------------- K1: zero everything + dtype detect (block 0) --------------
__global__ void setup_all(const unsigned* __restrict__ raw, int* flag,
                          int* cnt_r, int* cnt_h, float* uacc,
                          int2* spk_r, int2* spk_h, int N, int E, int EH){
  __shared__ int c;
  int t = blockIdx.x*blockDim.x + threadIdx.x;
  if (t < N){ cnt_r[t]=0; cnt_h[t]=0; }
  if (t < 64) uacc[t]=0.f;
  if (t < E)  spk_r[t]=make_int2(0,0);
  if (t < EH) spk_h[t]=make_int2(0,0);
  if (blockIdx.x==0){
    if (threadIdx.x==0) c=0;
    __syncthreads();
    unsigned u  = raw[threadIdx.x];
    unsigned lo = u & 0xFFFFu;
    int e = (int)((lo >> 7) & 0xFF);
    int ok = (lo==0u) || (e >= 0x70 && e <= 0x8F);
    atomicAdd(&c, ok);
    __syncthreads();
    if (threadIdx.x==0) *flag = (c >= 160) ? 1 : 0;  // 1 = bf16 storage
  }
}

// ---------------- K2: f32 convert || bf16 weight convert || edge count ------
__global__ __launch_bounds__(256) void convert_count(SegTable tbl, WTable wt,
    const int* __restrict__ flag,
    const int* __restrict__ ei, const int* __restrict__ eih,
    int E, int EH, int N, int* cnt_r, int* cnt_h, int CA, int CB){
  int b = blockIdx.x;
  if (b < CA){
    int mode = *flag;
    long tid    = (long)b*256 + threadIdx.x;
    long stride = (long)CA*256;
    for (long i=tid; i<tbl.total; i+=stride){
      long off = i; int k = 0;
      while (k < tbl.count-1 && off >= tbl.s[k].n){ off -= tbl.s[k].n; k++; }
      float f;
      if (mode) f = __bfloat162float(((const bf16*)tbl.s[k].src)[off]);
      else      f = ((const float*)tbl.s[k].src)[off];
      tbl.s[k].dst[off] = (f==f) ? f : 0.f;
    }
  } else if (b < CA+CB){
    int mode = *flag;
    long tid    = (long)(b-CA)*256 + threadIdx.x;
    long stride = (long)CB*256;
    for (long i=tid; i<wt.total; i+=stride){
      long off = i; int k = 0;
      while (k < wt.count-1 && off >= wt.s[k].n){ off -= wt.s[k].n; k++; }
      if (mode) wt.s[k].dst[off] = ((const ushort*)wt.s[k].src)[off];
      else {
        float f = ((const float*)wt.s[k].src)[off];
        wt.s[k].dst[off] = f2b((f==f)? f : 0.f);
      }
    }
  } else {
    int t = (b-CA-CB)*256 + threadIdx.x;
    if (t < E)  atomicAdd(&cnt_r[clampi(ei[E + t], 0, N-1)], 1);
    if (t < EH) atomicAdd(&cnt_h[clampi(eih[EH + t], 0, N-1)], 1);
  }
}

__global__ __launch_bounds__(1024) void scan_pair(const int* cnt_r, int* off_r, int* cur_r,
                                                  const int* cnt_h, int* off_h, int* cur_h, int N){
  __shared__ int s[1024];
  int t = threadIdx.x;
  int CH = (N + 1023) / 1024;
  for (int which=0; which<2; which++){
    const int* cnt = which? cnt_h : cnt_r;
    int* off = which? off_h : off_r;
    int* cur = which? cur_h : cur_r;
    int base = t*CH;
    int sum = 0;
    for (int q=0;q<CH;q++){ int idx=base+q; sum += (idx<N)? cnt[idx] : 0; }
    __syncthreads();
    s[t]=sum; __syncthreads();
    for (int ofs=1; ofs<1024; ofs<<=1){
      int v = s[t]; int vp = (t>=ofs)? s[t-ofs] : 0;
      __syncthreads(); s[t]=v+vp; __syncthreads();
    }
    int run = (t>0)? s[t-1] : 0;
    for (int q=0;q<CH;q++){
      int idx=base+q;
      if (idx<N){ off[idx]=run; cur[idx]=run; run += cnt[idx]; }
    }
    if (t==1023) off[N] = s[1023];
  }
}

// ---------------- K4a: scatter edges (standalone, lean) ---------------------
__global__ void scatter_edges(const int* __restrict__ ei, const float* __restrict__ distc,
                              const int* __restrict__ eih, int E, int EH, int N,
                              int* cur_r, int* cur_h, int2* spk_r, int2* spk_h){
  int t = blockIdx.x*blockDim.x + threadIdx.x;
  if (t < E){
    int i = clampi(ei[E+t], 0, N-1);
    int p = clampi(atomicAdd(&cur_r[i], 1), 0, E-1);
    float x = fminf(fmaxf(distc[t]*(4096.0f/5.0f), 0.f), 4095.999f);
    int i0 = (int)x; if (i0 > TBL_K-1) i0 = TBL_K-1;
    unsigned fr16 = (unsigned)((x - (float)i0)*65536.0f); if (fr16 > 65535u) fr16 = 65535u;
    spk_r[p] = make_int2(clampi(ei[t],0,N-1), (int)(((unsigned)i0<<16)|fr16));
  }
  if (t < EH){
    int ih = clampi(eih[EH+t], 0, N-1);
    int p = clampi(atomicAdd(&cur_h[ih], 1), 0, EH-1);
    spk_h[p] = make_int2(clampi(eih[t],0,N-1), t);
  }
}

// ------------------------------ MFMA tile helpers ---------------------------
__device__ __forceinline__ short8 afragb(const ushort (*Xb)[136], int lane, int k0){
  int m=lane&15, q=(lane>>4)&3;
  return *(const short8*)(&Xb[m][k0+q*8]);
}
__device__ __forceinline__ short8 bfrag(const ushort* __restrict__ W, int cbase, int lane, int k0){
  int n=lane&15, q=(lane>>4)&3;
  return *(const short8*)(W + (size_t)(cbase+n)*128 + k0 + q*8);
}
template<int NT>
__device__ __forceinline__ void mgemm(const ushort (*Xb)[136],
    const ushort* __restrict__ W, int t, f32x4 d[NT]){
  int lane=t&63, w=t>>6;
  #pragma unroll
  for (int ct=0;ct<NT;ct++) d[ct]=(f32x4){0.f,0.f,0.f,0.f};
  #pragma unroll
  for (int kc=0;kc<4;kc++){
    short8 a = afragb(Xb, lane, kc*32);
    #pragma unroll
    for (int ct=0;ct<NT;ct++){
      short8 b = bfrag(W, w*(NT*16)+ct*16, lane, kc*32);
      d[ct] = __builtin_amdgcn_mfma_f32_16x16x32_bf16(a, b, d[ct], 0, 0, 0);
    }
  }
}
template<int NT>
__device__ __forceinline__ void d2tile(ushort (*Y)[136], const f32x4 d[NT], int t,
    int colofs, const float* __restrict__ bias, int do_ssp){
  int lane=t&63, w=t>>6, q=(lane>>4)&3, n=lane&15;
  #pragma unroll
  for (int ct=0;ct<NT;ct++){
    int c = w*(NT*16)+ct*16+n;
    float bv = bias? bias[c] : 0.f;
    #pragma unroll
    for (int i=0;i<4;i++){
      float y = d[ct][i] + bv;
      if (do_ssp) y = dssp(y);
      Y[q*4+i][colofs+c] = f2b(y);
    }
  }
}
template<int NT>
__device__ __forceinline__ void d2os(float (*Os)[132], const f32x4 d[NT], int t,
    const float* __restrict__ bias, int do_ssp){
  int lane=t&63, w=t>>6, q=(lane>>4)&3, n=lane&15;
  #pragma unroll
  for (int ct=0;ct<NT;ct++){
    int c = w*(NT*16)+ct*16+n;
    float bv = bias? bias[c] : 0.f;
    #pragma unroll
    for (int i=0;i<4;i++){
      float y = d[ct][i] + bv;
      if (do_ssp) y = dssp(y);
      Os[q*4+i][c] = y;
    }
  }
}
__device__ __forceinline__ void d2glob_c(ushort* __restrict__ out, const f32x4 d[2],
    int t, int row0, int N, ushort (*Tmp)[136]){
  d2tile<2>(Tmp, d, t, 0, nullptr, 0);
  __syncthreads();
  int r=t>>4, o=(t&15)*8;
  int gr=row0+r;
  if (gr<N) *(uint4*)(out + (size_t)gr*128 + o) = *(const uint4*)&Tmp[r][o];
  __syncthreads();
}

// ---------------- K4b: W(dist) lookup table via MFMA (16-row tiles) ---------
__global__ __launch_bounds__(256) void build_wtab_mfma(
    const float* __restrict__ mlp_w1, const float* __restrict__ mlp_b1,
    const ushort* __restrict__ mlp_w2b, const float* __restrict__ mlp_b2,
    ushort* __restrict__ Wtab){
  int l    = blockIdx.x / TBL_T16;
  int tile = blockIdx.x % TBL_T16;
  int row0 = tile * 16;
  const float* w1 = mlp_w1 + l*128*25;
  const float* b1 = mlp_b1 + l*128;
  const ushort* w2 = mlp_w2b + (size_t)l*16384;
  const float* b2 = mlp_b2 + l*128;
  __shared__ float  Gs[16][26];
  __shared__ ushort Xb[16][136];
  __shared__ ushort Tb[16][136];
  int t = threadIdx.x;
  for (int idx=t; idx<16*25; idx+=256){
    int r=idx/25, k=idx%25;
    float dd = (row0+r) * (5.0f/4096.0f);
    float x  = dd - (float)k*(5.0f/24.0f);
    Gs[r][k] = __expf(-11.52f*x*x);
  }
  __syncthreads();
  { // layer 1: 8 consecutive cols per thread
    int r = t>>4, c0 = (t&15)*8;
    float fv[25];
    #pragma unroll
    for (int k=0;k<25;k++) fv[k]=Gs[r][k];
    short8 pk;
    #pragma unroll
    for (int j=0;j<8;j++){
      int c=c0+j;
      float s=b1[c];
      #pragma unroll
      for (int k=0;k<25;k++) s=fmaf(fv[k], w1[c*25+k], s);
      pk[j]=(short)f2b(dssp(s));
    }
    *(short8*)&Xb[r][c0]=pk;
  }
  __syncthreads();
  f32x4 d[2];
  mgemm<2>(Xb, w2, t, d);
  { // epilogue: bias + cutoff scale, stage bf16
    int lane=t&63, w=t>>6, q=(lane>>4)&3, n=lane&15;
    #pragma unroll
    for (int ct=0;ct<2;ct++){
      int c=w*32+ct*16+n;
      float bv=b2[c];
      #pragma unroll
      for (int i=0;i<4;i++){
        int gr=row0+q*4+i;
        float dd = gr*(5.0f/4096.0f);
        float Cf = 0.5f*(cosf(dd*(3.14159265358979f/5.0f))+1.0f);
        Tb[q*4+i][c]=f2b((d[ct][i]+bv)*Cf);
      }
    }
  }
  __syncthreads();
  int r=t>>4, o=(t&15)*8;
  int gr=row0+r;
  if (gr<TBL_ROWS)
    *(uint4*)(Wtab + ((size_t)l*TBL_ROWS+gr)*128 + o) = *(const uint4*)&Tb[r][o];
}

// ---- device bodies for hull tile + f_first tile (shared-mem passed in) -----
__device__ void hull_body(int bid, const int2* __restrict__ spk_h,
    const float* __restrict__ fea,
    const float* __restrict__ mlph_w1, const float* __restrict__ mlph_b1,
    const ushort* __restrict__ mlph_w2b, const float* __restrict__ mlph_b2,
    ushort* __restrict__ WhS_base, size_t lstride,
    int EH, int tilesPerLayer, int l0, char* smem){
  int l    = l0 + bid / tilesPerLayer;
  int tile = bid % tilesPerLayer;
  int row0 = tile*64;
  const float* w1 = mlph_w1 + l*128*7;
  const float* b1 = mlph_b1 + l*128;
  const ushort* w2 = mlph_w2b + (size_t)l*16384;
  const float* b2 = mlph_b2 + l*128;
  ushort* WhS = WhS_base + (size_t)(l-l0)*lstride;
  int*   Eid = (int*)smem;                       // 256 B
  float (*Fs)[8] = (float(*)[8])(smem+256);      // 2048 B
  ushort (*Buf)[136] = (ushort(*)[136])(smem+2304); // 17408 B
  int t=threadIdx.x;
  if (t < 64){
    int p=row0+t;
    Eid[t]=(p<EH)? clampi(spk_h[p].y,0,EH-1):0;
  }
  __syncthreads();
  for (int idx=t; idx<448; idx+=256){
    int r=idx/7, k=idx%7;
    int p=row0+r;
    Fs[r][k]=(p<EH)? fea[(size_t)Eid[r]*7+k]:0.f;
  }
  __syncthreads();
  {
    int c0=(t&31)*4, r0=(t>>5)*8;
    float w[4][7]; float bb[4];
    #pragma unroll
    for (int cc=0;cc<4;cc++){
      bb[cc]=b1[c0+cc];
      #pragma unroll
      for (int k=0;k<7;k++) w[cc][k]=w1[(c0+cc)*7+k];
    }
    #pragma unroll
    for (int rr=0;rr<8;rr++){
      int r=r0+rr;
      float fv[7];
      #pragma unroll
      for (int k=0;k<7;k++) fv[k]=Fs[r][k];
      ushort o[4];
      #pragma unroll
      for (int cc=0;cc<4;cc++){
        float s=bb[cc];
        #pragma unroll
        for (int k=0;k<7;k++) s=fmaf(fv[k],w[cc][k],s);
        o[cc]=f2b(dssp(s));
      }
      unsigned lo=(unsigned)o[0]|((unsigned)o[1]<<16);
      unsigned hi=(unsigned)o[2]|((unsigned)o[3]<<16);
      *(uint2*)&Buf[r][c0]=make_uint2(lo,hi);
    }
  }
  __syncthreads();
  int lane=t&63, w=t>>6;
  const ushort (*Xw)[136] = (const ushort (*)[136])&Buf[w*16][0];
  f32x4 d[8];
  #pragma unroll
  for (int ct=0;ct<8;ct++) d[ct]=(f32x4){0.f,0.f,0.f,0.f};
  #pragma unroll
  for (int kc=0;kc<4;kc++){
    short8 a = afragb(Xw, lane, kc*32);
    #pragma unroll
    for (int ct=0;ct<8;ct++){
      short8 b = bfrag(w2, ct*16, lane, kc*32);
      d[ct] = __builtin_amdgcn_mfma_f32_16x16x32_bf16(a, b, d[ct], 0, 0, 0);
    }
  }
  __syncthreads();
  int q=(lane>>4)&3, n=lane&15;
  #pragma unroll
  for (int ct=0;ct<8;ct++){
    int c=ct*16+n;
    float bv=b2[c];
    #pragma unroll
    for (int i=0;i<4;i++)
      Buf[w*16+q*4+i][c] = f2b(d[ct][i]+bv);
  }
  __syncthreads();
  #pragma unroll
  for (int j=0;j<4;j++){
    int idx=j*256+t;
    int r=idx>>4, o=(idx&15)*8;
    *(uint4*)(WhS + (size_t)(row0+r)*128 + o) = *(const uint4*)&Buf[r][o];
  }
}

__device__ void f_first_body(int bid, const int* __restrict__ z,
    const float* __restrict__ emb, float* __restrict__ v,
    const ushort* __restrict__ linA, const ushort* __restrict__ linB,
    ushort* __restrict__ vlin, ushort* __restrict__ vlinh, int N, char* smem){
  ushort (*Xb)[136] = (ushort(*)[136])smem;          // 4352 B
  ushort (*Tb)[136] = (ushort(*)[136])(smem+4352);   // 4352 B
  int t=threadIdx.x; int row0=bid*16;
  f32x4 d[2];
  for (int idx=t; idx<512; idx+=256){
    int r=idx>>5, k4=(idx&31)*4; int gr=row0+r;
    int zz=(gr<N)? clampi(z[gr],0,99):0;
    float4 f = *(const float4*)(emb + (size_t)zz*128 + k4);
    unsigned r0 = (unsigned)f2b(f.x) | ((unsigned)f2b(f.y)<<16);
    unsigned r1 = (unsigned)f2b(f.z) | ((unsigned)f2b(f.w)<<16);
    *(uint2*)&Xb[r][k4] = make_uint2(r0,r1);
    if (gr<N) *(float4*)(v + (size_t)gr*128 + k4) = f;
  }
  __syncthreads();
  mgemm<2>(Xb, linA, t, d);
  d2glob_c(vlin, d, t, row0, N, Tb);
  mgemm<2>(Xb, linB, t, d);
  d2glob_c(vlinh, d, t, row0, N, Tb);
}

// ------- K5: hull (all layers) || f_first || pack_wtab ----------------------
__global__ __launch_bounds__(256) void hull_pack_first(const int2* __restrict__ spk_h,
    const float* __restrict__ fea,
    const float* __restrict__ mlph_w1, const float* __restrict__ mlph_b1,
    const ushort* __restrict__ mlph_w2b, const float* __restrict__ mlph_b2,
    ushort* __restrict__ WhS, size_t lstride, int EH, int ht64,
    const int* __restrict__ z, const float* __restrict__ emb, float* __restrict__ v,
    const ushort* __restrict__ linA, const ushort* __restrict__ linB,
    ushort* __restrict__ vlin, ushort* __restrict__ vlinh, int N, int nt,
    const ushort* __restrict__ Wtab, unsigned* __restrict__ Wpk, int PB, int HB){
  __shared__ __align__(16) char smem[19968];
  int b = blockIdx.x;
  if (b < HB){
    hull_body(b, spk_h, fea, mlph_w1, mlph_b1, mlph_w2b, mlph_b2,
              WhS, lstride, EH, ht64, 0, smem);
  } else if (b < HB+nt){
    f_first_body(b-HB, z, emb, v, linA, linB, vlin, vlinh, N, smem);
  } else {
    long tid    = (long)(b-HB-nt)*256 + threadIdx.x;
    long stride = (long)PB*256;
    const long TOT = 4L*TBL_K*128;
    for (long i=tid; i<TOT; i+=stride){
      int l = (int)(i / ((long)TBL_K*128));
      long rem = i % ((long)TBL_K*128);
      int r = (int)(rem >> 7), f = (int)(rem & 127);
      const ushort* base = Wtab + (size_t)l*TBL_ROWS*128;
      Wpk[i] = (((unsigned)base[(size_t)(r+1)*128+f])<<16) | (unsigned)base[(size_t)r*128+f];
    }
  }
}

// standalone hull (fallback when workspace can't hold 4 layers)
__global__ __launch_bounds__(256) void hull_all(const int2* __restrict__ spk_h,
    const float* __restrict__ fea,
    const float* __restrict__ mlph_w1, const float* __restrict__ mlph_b1,
    const ushort* __restrict__ mlph_w2b, const float* __restrict__ mlph_b2,
    ushort* __restrict__ WhS_base, size_t lstride,
    int EH, int tilesPerLayer, int l0){
  __shared__ __align__(16) char smem[19968];
  hull_body(blockIdx.x, spk_h, fea, mlph_w1, mlph_b1, mlph_w2b, mlph_b2,
            WhS_base, lstride, EH, tilesPerLayer, l0, smem);
}

// -------------- F_mid: update_v(l) + lin(l+1) + linh(l+1) -------------------
__global__ __launch_bounds__(256) void f_mid(
    const float* __restrict__ accR, const float* __restrict__ accH,
    float* __restrict__ v,
    const ushort* __restrict__ v1w, const float* __restrict__ v1b,
    const ushort* __restrict__ v2w, const float* __restrict__ v2b,
    const ushort* __restrict__ vh1w, const float* __restrict__ vh1b,
    const ushort* __restrict__ vh2w, const float* __restrict__ vh2b,
    const ushort* __restrict__ cw, const float* __restrict__ cb,
    const ushort* __restrict__ linA, const ushort* __restrict__ linB,
    ushort* __restrict__ vlin, ushort* __restrict__ vlinh, int N){
  __shared__ ushort Xb[16][136];
  __shared__ ushort Xb2[16][136];
  __shared__ ushort Xb3[16][136];
  __shared__ float  Os[16][132];
  int t=threadIdx.x; int row0=blockIdx.x*16;
  f32x4 d[2]; f32x4 d1[1];

  for (int path=0; path<2; path++){
    const float* X = path? accH : accR;
    __syncthreads();
    for (int idx=t; idx<512; idx+=256){
      int r=idx>>5, k4=(idx&31)*4; int gr=row0+r;
      float4 f=(gr<N)? *(const float4*)(X+(size_t)gr*128+k4):make_float4(0,0,0,0);
      unsigned r0 = (unsigned)f2b(f.x) | ((unsigned)f2b(f.y)<<16);
      unsigned r1 = (unsigned)f2b(f.z) | ((unsigned)f2b(f.w)<<16);
      *(uint2*)&Xb[r][k4] = make_uint2(r0,r1);
    }
    __syncthreads();
    mgemm<2>(Xb, path?vh1w:v1w, t, d);
    d2tile<2>(Xb2, d, t, 0, path?vh1b:v1b, 1);
    __syncthreads();
    mgemm<1>(Xb2, path?vh2w:v2w, t, d1);
    d2tile<1>(Xb3, d1, t, path*64, path?vh2b:v2b, 0);
  }
  __syncthreads();
  mgemm<2>(Xb3, cw, t, d);
  d2os<2>(Os, d, t, cb, 1);
  __syncthreads();
  for (int idx=t; idx<512; idx+=256){      // v += Os ; Xb = bf16(new v)
    int r=idx>>5, k4=(idx&31)*4; int gr=row0+r;
    float4 f=(gr<N)? *(const float4*)(v+(size_t)gr*128+k4):make_float4(0,0,0,0);
    f.x+=Os[r][k4]; f.y+=Os[r][k4+1]; f.z+=Os[r][k4+2]; f.w+=Os[r][k4+3];
    if (gr<N) *(float4*)(v+(size_t)gr*128+k4)=f;
    unsigned r0 = (unsigned)f2b(f.x) | ((unsigned)f2b(f.y)<<16);
    unsigned r1 = (unsigned)f2b(f.z) | ((unsigned)f2b(f.w)<<16);
    *(uint2*)&Xb[r][k4] = make_uint2(r0,r1);
  }
  __syncthreads();
  mgemm<2>(Xb, linA, t, d);
  d2glob_c(vlin, d, t, row0, N, Xb2);
  mgemm<2>(Xb, linB, t, d);
  d2glob_c(vlinh, d, t, row0, N, Xb2);
}

// -------------- F_last: update_v(3) + readout (update_u) --------------------
__global__ __launch_bounds__(256) void f_last(
    const float* __restrict__ accR, const float* __restrict__ accH,
    const float* __restrict__ v,
    const ushort* __restrict__ v1w, const float* __restrict__ v1b,
    const ushort* __restrict__ v2w, const float* __restrict__ v2b,
    const ushort* __restrict__ vh1w, const float* __restrict__ vh1b,
    const ushort* __restrict__ vh2w, const float* __restrict__ vh2b,
    const ushort* __restrict__ cw, const float* __restrict__ cb,
    const ushort* __restrict__ u1w, const float* __restrict__ u1b,
    const float* __restrict__ u2w, const float* __restrict__ u2b,
    const int* __restrict__ batch, float* __restrict__ uacc, int N){
  __shared__ ushort Xb[16][136];
  __shared__ ushort Xb2[16][136];
  __shared__ ushort Xb3[16][136];
  __shared__ float  Os[16][132];
  __shared__ float ss[16];
  __shared__ int   bb[16];
  int t=threadIdx.x; int row0=blockIdx.x*16;
  f32x4 d[2]; f32x4 d1[1];

  for (int path=0; path<2; path++){
    const float* X = path? accH : accR;
    __syncthreads();
    for (int idx=t; idx<512; idx+=256){
      int r=idx>>5, k4=(idx&31)*4; int gr=row0+r;
      float4 f=(gr<N)? *(const float4*)(X+(size_t)gr*128+k4):make_float4(0,0,0,0);
      unsigned r0 = (unsigned)f2b(f.x) | ((unsigned)f2b(f.y)<<16);
      unsigned r1 = (unsigned)f2b(f.z) | ((unsigned)f2b(f.w)<<16);
      *(uint2*)&Xb[r][k4] = make_uint2(r0,r1);
    }
    __syncthreads();
    mgemm<2>(Xb, path?vh1w:v1w, t, d);
    d2tile<2>(Xb2, d, t, 0, path?vh1b:v1b, 1);
    __syncthreads();
    mgemm<1>(Xb2, path?vh2w:v2w, t, d1);
    d2tile<1>(Xb3, d1, t, path*64, path?vh2b:v2b, 0);
  }
  __syncthreads();
  mgemm<2>(Xb3, cw, t, d);
  d2os<2>(Os, d, t, cb, 1);
  __syncthreads();
  for (int idx=t; idx<512; idx+=256){      // Xb = bf16(v + dssp(cat))
    int r=idx>>5, k4=(idx&31)*4; int gr=row0+r;
    float4 f=(gr<N)? *(const float4*)(v+(size_t)gr*128+k4):make_float4(0,0,0,0);
    f.x+=Os[r][k4]; f.y+=Os[r][k4+1]; f.z+=Os[r][k4+2]; f.w+=Os[r][k4+3];
    unsigned r0 = (unsigned)f2b(f.x) | ((unsigned)f2b(f.y)<<16);
    unsigned r1 = (unsigned)f2b(f.z) | ((unsigned)f2b(f.w)<<16);
    *(uint2*)&Xb[r][k4] = make_uint2(r0,r1);
  }
  __syncthreads();
  mgemm<1>(Xb, u1w, t, d1);                // 64 cols
  d2os<1>(Os, d1, t, u1b, 1);
  __syncthreads();
  if (t<16){
    int gr=row0+t;
    float s=0.f; int bt=-1;
    if (gr<N){
      s = u2b[0];
      for (int c=0;c<64;c++) s += Os[t][c]*u2w[c];
      bt = clampi(batch[gr],0,63);
    }
    ss[t]=s; bb[t]=bt;
  }
  __syncthreads();
  if (t==0){
    float run=0.f; int cur=-1;
    for (int q=0;q<16;q++){
      int bq=bb[q];
      if (bq<0) continue;
      if (bq!=cur){ if (cur>=0) atomicAdd(&uacc[cur],run); cur=bq; run=0.f; }
      run += ss[q];
    }
    if (cur>=0) atomicAdd(&uacc[cur],run);
  }
}

// ------------------------------ CSR segment reductions ----------------------
__device__ __forceinline__ float rlerp(unsigned y, const unsigned* __restrict__ Wpk, int f){
  int i0 = (int)(y>>16);
  float fr = (float)(y&0xFFFFu)*(1.f/65536.f);
  unsigned u = Wpk[(size_t)i0*128+f];
  float w0=__uint_as_float(u<<16), w1=__uint_as_float(u&0xFFFF0000u);
  return fmaf(fr, w1-w0, w0);
}

__global__ __launch_bounds__(128) void acc_both(
    const int* __restrict__ off_r, const int2* __restrict__ spk_r,
    const ushort* __restrict__ vlin, const unsigned* __restrict__ Wpk,
    float* __restrict__ accR,
    const int* __restrict__ off_h, const int2* __restrict__ spk_h,
    const ushort* __restrict__ vlinh, const ushort* __restrict__ WhS,
    float* __restrict__ accH,
    int Etot, int EHtot, int N){
  int f = threadIdx.x;
  if ((int)blockIdx.x < N){
    int n = blockIdx.x;
    int b = clampi(off_r[n], 0, Etot);
    int e = clampi(off_r[n+1], b, Etot);
    float a = 0.f;
    int p = b;
    for (; p+8<=e; p+=8){
      int2 k[8];
      #pragma unroll
      for (int j=0;j<8;j++) k[j]=spk_r[p+j];
      float vv[8], ww[8];
      #pragma unroll
      for (int j=0;j<8;j++) vv[j]=b2f16(vlin[(size_t)k[j].x*128+f]);
      #pragma unroll
      for (int j=0;j<8;j++) ww[j]=rlerp((unsigned)k[j].y, Wpk, f);
      #pragma unroll
      for (int j=0;j<8;j++) a=fmaf(vv[j],ww[j],a);
    }
    for (; p+4<=e; p+=4){
      int2 k0=spk_r[p], k1=spk_r[p+1], k2=spk_r[p+2], k3=spk_r[p+3];
      float v0 = b2f16(vlin[(size_t)k0.x*128+f]);
      float v1 = b2f16(vlin[(size_t)k1.x*128+f]);
      float v2 = b2f16(vlin[(size_t)k2.x*128+f]);
      float v3 = b2f16(vlin[(size_t)k3.x*128+f]);
      float w0 = rlerp((unsigned)k0.y, Wpk, f);
      float w1 = rlerp((unsigned)k1.y, Wpk, f);
      float w2 = rlerp((unsigned)k2.y, Wpk, f);
      float w3 = rlerp((unsigned)k3.y, Wpk, f);
      a += v0*w0 + v1*w1 + v2*w2 + v3*w3;
    }
    for (; p<e; p++){
      int2 k0=spk_r[p];
      a += b2f16(vlin[(size_t)k0.x*128+f]) * rlerp((unsigned)k0.y, Wpk, f);
    }
    accR[(size_t)n*128+f] = a;
  } else {
    int n = blockIdx.x - N;
    int b = clampi(off_h[n], 0, EHtot);
    int e = clampi(off_h[n+1], b, EHtot);
    float a = 0.f;
    int p = b;
    for (; p+4<=e; p+=4){
      int2 k0=spk_h[p], k1=spk_h[p+1], k2=spk_h[p+2], k3=spk_h[p+3];
      float v0 = b2f16(vlinh[(size_t)k0.x*128+f]);
      float v1 = b2f16(vlinh[(size_t)k1.x*128+f]);
      float v2 = b2f16(vlinh[(size_t)k2.x*128+f]);
      float v3 = b2f16(vlinh[(size_t)k3.x*128+f]);
      a += v0*b2f16(WhS[(size_t)p*128+f])     + v1*b2f16(WhS[(size_t)(p+1)*128+f])
         + v2*b2f16(WhS[(size_t)(p+2)*128+f]) + v3*b2f16(WhS[(size_t)(p+3)*128+f]);
    }
    for (; p<e; p++){
      int2 k0=spk_h[p];
      a += b2f16(vlinh[(size_t)k0.x*128+f]) * b2f16(WhS[(size_t)p*128+f]);
    }
    accH[(size_t)n*128+f] = a;
  }
}

__global__ void write_out(const float* __restrict__ uacc, void* out, const int* __restrict__ flag){
  int t = threadIdx.x;
  if (t < 64){
    if (*flag) ((bf16*)out)[t] = __float2bfloat16(uacc[t]);
    else       ((float*)out)[t] = uacc[t];
  }
}

// ----------------------------------------------------------------- launch ---
extern "C" void kernel_launch(void* const* d_in, const int* in_sizes, int n_in,
                              void* d_out, int out_size, void* d_ws, size_t ws_size,
                              hipStream_t stream){
  const int* z     = (const int*)d_in[0];
  const int* ei    = (const int*)d_in[1];
  const int* eih   = (const int*)d_in[2];
  const int* batch = (const int*)d_in[3];

  const int N  = in_sizes[0];
  const int E  = in_sizes[1]/2;
  const int EH = in_sizes[2]/2;
  const int EHpad = (EH + 63) & ~63;

  char* wp = (char*)d_ws;
  auto alloc = [&](size_t bytes)->char*{
    char* p = wp; wp += (bytes + 255) & ~(size_t)255; return p;
  };
  int* flag    = (int*)alloc(256);
  int* cnt_r   = (int*)alloc((size_t)N*4);
  int* off_r   = (int*)alloc((size_t)(N+1)*4);
  int* cur_r   = (int*)alloc((size_t)N*4);
  int* cnt_h   = (int*)alloc((size_t)N*4);
  int* off_h   = (int*)alloc((size_t)(N+1)*4);
  int* cur_h   = (int*)alloc((size_t)N*4);
  int2* spk_r  = (int2*)alloc((size_t)E*8);
  int2* spk_h  = (int2*)alloc((size_t)EH*8);
  float* uacc  = (float*)alloc(64*4);

  // fp32 canonical copies: only tensors consumed as fp32 downstream
  static const int f32_idx[17] = {0,1,2,4,5,7,9,10,12,14,16,18,20,22,24,25,26};
  float* cvt[27] = {};
  SegTable tbl; tbl.count = 17; tbl.total = 0;
  for (int k=0;k<17;k++){
    int i = f32_idx[k];
    int n = in_sizes[4+i];
    cvt[i] = (float*)alloc((size_t)n*4);
    tbl.s[k].src = d_in[4+i];
    tbl.s[k].dst = cvt[i];
    tbl.s[k].n   = n;
    tbl.total   += n;
  }
  const float* distc   = cvt[0];
  const float* feac    = cvt[1];
  const float* embc    = cvt[2];
  const float* mlp_w1  = cvt[4];
  const float* mlp_b1  = cvt[5];
  const float* mlp_b2  = cvt[7];
  const float* mlph_w1 = cvt[9];
  const float* mlph_b1 = cvt[10];
  const float* mlph_b2 = cvt[12];
  const float* v1_b  = cvt[14];
  const float* v2_b  = cvt[16];
  const float* vh1_b = cvt[18];
  const float* vh2_b = cvt[20];
  const float* cat_b = cvt[22];
  const float* u1_b  = cvt[24];
  const float* u2_w  = cvt[25];
  const float* u2_b  = cvt[26];

  // bf16 weight copies, converted directly from inputs
  ushort* lin_wb   = (ushort*)alloc((size_t)4*16384*2);
  ushort* linh_wb  = (ushort*)alloc((size_t)4*16384*2);
  ushort* v1_wb    = (ushort*)alloc((size_t)4*16384*2);
  ushort* vh1_wb   = (ushort*)alloc((size_t)4*16384*2);
  ushort* cat_wb   = (ushort*)alloc((size_t)4*16384*2);
  ushort* mlph_w2b = (ushort*)alloc((size_t)4*16384*2);
  ushort* mlp_w2b  = (ushort*)alloc((size_t)4*16384*2);
  ushort* v2_wb    = (ushort*)alloc((size_t)4*8192*2);
  ushort* vh2_wb   = (ushort*)alloc((size_t)4*8192*2);
  ushort* u1_wb    = (ushort*)alloc((size_t)8192*2);
  WTable wt; wt.count = 10;
  wt.s[0] = { d_in[4+3],  lin_wb,   4*16384 };
  wt.s[1] = { d_in[4+6],  mlp_w2b,  4*16384 };
  wt.s[2] = { d_in[4+8],  linh_wb,  4*16384 };
  wt.s[3] = { d_in[4+11], mlph_w2b, 4*16384 };
  wt.s[4] = { d_in[4+13], v1_wb,    4*16384 };
  wt.s[5] = { d_in[4+15], v2_wb,    4*8192  };
  wt.s[6] = { d_in[4+17], vh1_wb,   4*16384 };
  wt.s[7] = { d_in[4+19], vh2_wb,   4*8192  };
  wt.s[8] = { d_in[4+21], cat_wb,   4*16384 };
  wt.s[9] = { d_in[4+23], u1_wb,    8192    };
  wt.total = 7*4*16384 + 2*4*8192 + 8192;

  ushort*   Wtab = (ushort*)alloc((size_t)4*TBL_ROWS*128*2);
  unsigned* Wpk  = (unsigned*)alloc((size_t)4*TBL_K*128*4);
  float* v     = (float*)alloc((size_t)N*128*4);
  ushort* vlin  = (ushort*)alloc((size_t)N*128*2);
  ushort* vlinh = (ushort*)alloc((size_t)N*128*2);
  float* accR  = (float*)alloc((size_t)N*128*4);
  float* accH  = (float*)alloc((size_t)N*128*4);

  size_t used = (size_t)(wp - (char*)d_ws);
  size_t whs1 = (size_t)EHpad*128*2;
  bool pre = (ws_size >= used + 4*whs1 + 256);
  ushort* WhS = (ushort*)alloc(pre ? 4*whs1 : whs1);

  const int nbE  = (E+255)/256;
  const int nt   = (N+15)/16;
  const int ht64 = (EH+63)/64;
  const int CA = 1536, CB = 1024, PB = 1024;

  // K1: zero + detect
  setup_all<<<nbE,256,0,stream>>>((const unsigned*)d_in[6], flag,
                                  cnt_r, cnt_h, uacc, spk_r, spk_h, N, E, EH);
  // K2: convert (f32 + bf16) || count
  convert_count<<<CA+CB+nbE,256,0,stream>>>(tbl, wt, flag, ei, eih, E, EH, N,
                                            cnt_r, cnt_h, CA, CB);
  // K3: scan
  scan_pair<<<1,1024,0,stream>>>(cnt_r,off_r,cur_r,cnt_h,off_h,cur_h,N);
  // K4a: scatter (lean)
  scatter_edges<<<nbE,256,0,stream>>>(ei, distc, eih, E, EH, N,
                                      cur_r, cur_h, spk_r, spk_h);
  // K4b: build W-table via MFMA
  build_wtab_mfma<<<4*TBL_T16,256,0,stream>>>(mlp_w1, mlp_b1, mlp_w2b, mlp_b2, Wtab);
  // K5: hull(all layers, if pre) || f_first || pack_wtab
  {
    int HB = pre ? 4*ht64 : 0;
    hull_pack_first<<<HB+nt+PB,256,0,stream>>>(spk_h, feac, mlph_w1, mlph_b1,
        mlph_w2b, mlph_b2, WhS, whs1/2, EH, ht64,
        z, embc, v, lin_wb, linh_wb, vlin, vlinh, N, nt,
        Wtab, Wpk, PB, HB);
  }

  for (int l=0;l<4;l++){
    if (!pre)
      hull_all<<<ht64,256,0,stream>>>(spk_h, feac, mlph_w1, mlph_b1, mlph_w2b, mlph_b2,
                                      WhS, 0, EH, ht64, l);
    const ushort* WhSl = pre ? (WhS + (size_t)l*(whs1/2)) : WhS;
    acc_both<<<2*N,128,0,stream>>>(off_r, spk_r, vlin, Wpk + (size_t)l*TBL_K*128, accR,
                                   off_h, spk_h, vlinh, WhSl, accH, E, EH, N);
    if (l<3){
      f_mid<<<nt,256,0,stream>>>(accR, accH, v,
          v1_wb + (size_t)l*16384, v1_b + l*128, v2_wb + (size_t)l*8192, v2_b + l*64,
          vh1_wb + (size_t)l*16384, vh1_b + l*128, vh2_wb + (size_t)l*8192, vh2_b + l*64,
          cat_wb + (size_t)l*16384, cat_b + l*128,
          lin_wb + (size_t)(l+1)*16384, linh_wb + (size_t)(l+1)*16384, vlin, vlinh, N);
    } else {
      f_last<<<nt,256,0,stream>>>(accR, accH, v,
          v1_wb + (size_t)l*16384, v1_b + l*128, v2_wb + (size_t)l*8192, v2_b + l*64,
          vh1_wb + (size_t)l*16384, vh1_b + l*128, vh2_wb + (size_t)l*8192, vh2_b + l*64,
          cat_wb + (size_t)l*16384, cat_b + l*128,
          u1_wb, u1_b, u2_w, u2_b, batch, uacc, N);
    }
  }
  write_out<<<1,64,0,stream>>>(uacc, d_out, flag);
}